// Round 4
// baseline (342.899 us; speedup 1.0000x reference)
//
#include <hip/hip_runtime.h>
#include <cstddef>

#define NB    4
#define CIN   32
#define COUT  64
#define NFINE 163842
#define NSV   40962
#define EPSB  1e-5f
#define SLOPE 0.2f

typedef __attribute__((ext_vector_type(8))) short short8;
typedef __attribute__((ext_vector_type(4))) float f32x4;

// ws layout (bytes):
//   O_XT  : xt bf16 [B][NFINE][32] (41.9 MB) -- dead after k_pool
//   O_H   : h  bf16 [B][NSV][64]   (21 MB)   -- aliases xt (written after k_pool)
//   O_POOL: pooled bf16 [B][NSV][32] (10.5 MB)
//   O_W1F : W1 frag-major bf16 (28 KB)
//   O_WCF : Wc frag-major bf16 (16 KB)
//   O_ST  : f32 sum[64] sq[64] scale[64] shift[64]
#define O_XT   ((size_t)0)
#define O_H    ((size_t)0)
#define O_POOL ((size_t)48 << 20)
#define O_W1F  ((size_t)60 << 20)
#define O_WCF  ((size_t)60 << 20 | 0x8000)
#define O_ST   ((size_t)61 << 20)

static __device__ __forceinline__ short f2bf(float f) {
    union { float f; unsigned u; } v; v.f = f;
    unsigned r = v.u + 0x7fffu + ((v.u >> 16) & 1u);   // RNE
    return (short)(r >> 16);
}
static __device__ __forceinline__ float bf2f(short h) {
    union { unsigned u; float f; } v;
    v.u = ((unsigned)(unsigned short)h) << 16;
    return v.f;
}

// zero stats + build frag-major weights
// W1f: [kk<7][nf<4][l<64][e<8], o=16nf+(l&15), k=32kk+8(l>>4)+e
// Wcf: [kk<4][nf<4][l<64][e<8], o=16nf+(l&15), c=32kk+8(l>>4)+e
__global__ void k_prep(const float* __restrict__ W1, const float* __restrict__ Wc,
                       short* __restrict__ W1f, short* __restrict__ Wcf,
                       float* __restrict__ stats) {
    if (threadIdx.x < 128) stats[threadIdx.x] = 0.f;
    for (int i = threadIdx.x; i < 7 * 4 * 64 * 8; i += 256) {
        int e = i & 7, l = (i >> 3) & 63, nf = (i >> 9) & 3, kk = i >> 11;
        int o = 16 * nf + (l & 15);
        int k = 32 * kk + 8 * (l >> 4) + e;
        W1f[i] = f2bf(W1[o * (7 * CIN) + k]);
    }
    for (int i = threadIdx.x; i < 4 * 4 * 64 * 8; i += 256) {
        int e = i & 7, l = (i >> 3) & 63, nf = (i >> 9) & 3, kk = i >> 11;
        int o = 16 * nf + (l & 15);
        int c = 32 * kk + 8 * (l >> 4) + e;
        Wcf[i] = f2bf(Wc[o * (2 * COUT) + c]);
    }
}

// x [B][CIN][NFINE] f32 -> xt [B][NFINE][CIN] bf16
__global__ __launch_bounds__(256) void k_transpose(
        const float* __restrict__ x, short* __restrict__ xt) {
    __shared__ float tile[128][33];
    const int n0 = blockIdx.x * 128;
    const int b  = blockIdx.y;
    const float* xb = x + (size_t)b * CIN * NFINE;
#pragma unroll
    for (int q = 0; q < 16; ++q) {
        int i = threadIdx.x + 256 * q;
        int c = i >> 7, nl = i & 127;
        int n = n0 + nl;
        tile[nl][c] = (n < NFINE) ? xb[(size_t)c * NFINE + n] : 0.f;
    }
    __syncthreads();
#pragma unroll
    for (int q = 0; q < 2; ++q) {
        int i = threadIdx.x + 256 * q;
        int nl = i >> 2, cg = i & 3;
        int n = n0 + nl;
        if (n >= NFINE) continue;
        short8 o;
#pragma unroll
        for (int e = 0; e < 8; ++e) o[e] = f2bf(tile[nl][8 * cg + e]);
        *(short8*)(xt + ((size_t)b * NFINE + n) * CIN + 8 * cg) = o;
    }
}

// pooled[b][s][c] = mean_j xt[b][pool_neigh[7s+j]][c]
// All 7 indices loaded first; per-16B phase all 7 gathers issued before use.
__global__ __launch_bounds__(256) void k_pool(
        const short* __restrict__ xt, const int* __restrict__ pn,
        short* __restrict__ pooled) {
    const int s = blockIdx.x * 256 + threadIdx.x;
    const int b = blockIdx.y;
    if (s >= NSV) return;
    int t[7];
#pragma unroll
    for (int j = 0; j < 7; ++j) t[j] = pn[7 * s + j];
    const short* xb = xt + (size_t)b * NFINE * CIN;
    short* op = pooled + ((size_t)b * NSV + s) * CIN;
#pragma unroll
    for (int gq = 0; gq < 4; ++gq) {
        short8 v[7];
#pragma unroll
        for (int j = 0; j < 7; ++j)
            v[j] = *(const short8*)(xb + (size_t)t[j] * CIN + 8 * gq);
        float a8[8];
#pragma unroll
        for (int e = 0; e < 8; ++e) a8[e] = 0.f;
#pragma unroll
        for (int j = 0; j < 7; ++j)
#pragma unroll
            for (int e = 0; e < 8; ++e) a8[e] += bf2f(v[j][e]);
        short8 o;
#pragma unroll
        for (int e = 0; e < 8; ++e) o[e] = f2bf(a8[e] * (1.f / 7.f));
        *(short8*)(op + 8 * gq) = o;
    }
}

// MFMA conv: h[b][s][o] = sum_k A[s][k] * W1T[k][o]  (K=224, b1 cancels in BN)
// Full A-prefetch: 14 indices -> 14 fragment gathers in flight -> 56 MFMAs.
__global__ __launch_bounds__(256) void k_conv(
        const int* __restrict__ neigh, const short* __restrict__ W1f,
        const short* __restrict__ pooled, short* __restrict__ hbf,
        float* __restrict__ stats) {
    __shared__ float red[2][4][COUT];
    const int l = threadIdx.x & 63, w = threadIdx.x >> 6;
    const int b = blockIdx.y;
    const int s0 = blockIdx.x * 128 + w * 32;
    const int r = l & 15, g = l >> 4;

    const short* pb = pooled + (size_t)b * NSV * CIN;
    const int sA0 = s0 + r, sA1 = s0 + 16 + r;
    const bool v0 = sA0 < NSV, v1 = sA1 < NSV;
    const int c0 = v0 ? sA0 : NSV - 1, c1 = v1 ? sA1 : NSV - 1;

    int t0[7], t1[7];
#pragma unroll
    for (int kk = 0; kk < 7; ++kk) { t0[kk] = neigh[7 * c0 + kk]; t1[kk] = neigh[7 * c1 + kk]; }

    short8 a0[7], a1[7];
#pragma unroll
    for (int kk = 0; kk < 7; ++kk) {
        a0[kk] = *(const short8*)(pb + (size_t)t0[kk] * CIN + 8 * g);
        a1[kk] = *(const short8*)(pb + (size_t)t1[kk] * CIN + 8 * g);
    }

    f32x4 acc[2][4];
#pragma unroll
    for (int mf = 0; mf < 2; ++mf)
#pragma unroll
        for (int nf = 0; nf < 4; ++nf) acc[mf][nf] = (f32x4){0.f, 0.f, 0.f, 0.f};

#pragma unroll
    for (int kk = 0; kk < 7; ++kk) {
        const short8* wf = (const short8*)(W1f) + (size_t)kk * 256;
#pragma unroll
        for (int nf = 0; nf < 4; ++nf) {
            short8 bfv = wf[nf * 64 + l];
            acc[0][nf] = __builtin_amdgcn_mfma_f32_16x16x32_bf16(a0[kk], bfv, acc[0][nf], 0, 0, 0);
            acc[1][nf] = __builtin_amdgcn_mfma_f32_16x16x32_bf16(a1[kk], bfv, acc[1][nf], 0, 0, 0);
        }
    }

    float sum[4], sq[4];
#pragma unroll
    for (int nf = 0; nf < 4; ++nf) { sum[nf] = 0.f; sq[nf] = 0.f; }
#pragma unroll
    for (int mf = 0; mf < 2; ++mf)
#pragma unroll
        for (int nf = 0; nf < 4; ++nf) {
            f32x4 d = acc[mf][nf];
#pragma unroll
            for (int rr = 0; rr < 4; ++rr) {
                const int srow = s0 + 16 * mf + 4 * g + rr;
                const float v = d[rr];
                const bool ok = srow < NSV;
                if (ok) hbf[((size_t)b * NSV + srow) * COUT + 16 * nf + r] = f2bf(v);
                const float vm = ok ? v : 0.f;
                sum[nf] += vm; sq[nf] += vm * vm;
            }
        }
#pragma unroll
    for (int nf = 0; nf < 4; ++nf) {
        float a = sum[nf], c = sq[nf];
        a += __shfl_xor(a, 16); a += __shfl_xor(a, 32);
        c += __shfl_xor(c, 16); c += __shfl_xor(c, 32);
        if (g == 0) { red[0][w][16 * nf + r] = a; red[1][w][16 * nf + r] = c; }
    }
    __syncthreads();
    if (threadIdx.x < COUT) {
        const int o = threadIdx.x;
        atomicAdd(&stats[o],        red[0][0][o] + red[0][1][o] + red[0][2][o] + red[0][3][o]);
        atomicAdd(&stats[COUT + o], red[1][0][o] + red[1][1][o] + red[1][2][o] + red[1][3][o]);
    }
}

__global__ void k_stats(const float* __restrict__ gamma,
                        const float* __restrict__ beta, float* __restrict__ st) {
    const int o = threadIdx.x;  // 64
    const float cnt = (float)((size_t)NB * NSV);
    float mu  = st[o] / cnt;
    float var = st[COUT + o] / cnt - mu * mu;
    float sc  = gamma[o] * rsqrtf(var + EPSB);
    st[2 * COUT + o] = sc;
    st[3 * COUT + o] = beta[o] - mu * sc;
}

// MFMA out: out[b][o][s] = sum_c A[s][c] * WcT[c][o] + bc[o]
//   A[s][0:64]   = leaky(sc*h[b][s][:]+sh)  (from hbf, bf16)
//   A[s][64:128] = x1[b][:][s]              (read directly, f32 strided-coalesced)
__global__ __launch_bounds__(256) void k_out(
        const short* __restrict__ hbf, const float* __restrict__ x1,
        const short* __restrict__ Wcf, const float* __restrict__ st,
        const float* __restrict__ bc, float* __restrict__ out) {
    __shared__ __attribute__((aligned(16))) short Wcs[4 * 4 * 64 * 8]; // 16KB
    __shared__ float scs[COUT], shs[COUT], bcs[COUT];
    {
        const short8* src = (const short8*)Wcf;
        short8* dst = (short8*)Wcs;
        for (int i = threadIdx.x; i < 1024; i += 256) dst[i] = src[i];
        if (threadIdx.x < COUT) {
            scs[threadIdx.x] = st[2 * COUT + threadIdx.x];
            shs[threadIdx.x] = st[3 * COUT + threadIdx.x];
            bcs[threadIdx.x] = bc[threadIdx.x];
        }
    }
    __syncthreads();

    const int l = threadIdx.x & 63, w = threadIdx.x >> 6;
    const int b = blockIdx.y;
    const int s0 = blockIdx.x * 128 + w * 32;
    const int r = l & 15, g = l >> 4;

    int sa0 = s0 + r;       if (sa0 > NSV - 1) sa0 = NSV - 1;
    int sa1 = s0 + 16 + r;  if (sa1 > NSV - 1) sa1 = NSV - 1;
    const size_t rowA0 = ((size_t)b * NSV + sa0) * COUT;
    const size_t rowA1 = ((size_t)b * NSV + sa1) * COUT;

    // ---- prefetch everything: 4 h-fragments + 32 x1 scalars ----
    short8 h00 = *(const short8*)(hbf + rowA0 + 8 * g);
    short8 h01 = *(const short8*)(hbf + rowA0 + 32 + 8 * g);
    short8 h10 = *(const short8*)(hbf + rowA1 + 8 * g);
    short8 h11 = *(const short8*)(hbf + rowA1 + 32 + 8 * g);
    const float* x1b = x1 + (size_t)b * COUT * NSV;
    float xv0[16], xv1[16];
#pragma unroll
    for (int i = 0; i < 16; ++i) {
        const int c2 = 32 * (i >> 3) + 8 * g + (i & 7);  // x1 channel
        xv0[i] = x1b[(size_t)c2 * NSV + sa0];
        xv1[i] = x1b[(size_t)c2 * NSV + sa1];
    }

    float scv[16], shv[16];
#pragma unroll
    for (int kk = 0; kk < 2; ++kk)
#pragma unroll
        for (int e = 0; e < 8; ++e) {
            scv[8 * kk + e] = scs[32 * kk + 8 * g + e];
            shv[8 * kk + e] = shs[32 * kk + 8 * g + e];
        }

    f32x4 acc[2][4];
#pragma unroll
    for (int mf = 0; mf < 2; ++mf)
#pragma unroll
        for (int nf = 0; nf < 4; ++nf) acc[mf][nf] = (f32x4){0.f, 0.f, 0.f, 0.f};

#pragma unroll
    for (int kk = 0; kk < 4; ++kk) {
        short8 a0, a1;
        if (kk < 2) {
            short8 hh0 = kk ? h01 : h00;
            short8 hh1 = kk ? h11 : h10;
#pragma unroll
            for (int e = 0; e < 8; ++e) {
                float z0 = scv[8 * kk + e] * bf2f(hh0[e]) + shv[8 * kk + e];
                float z1 = scv[8 * kk + e] * bf2f(hh1[e]) + shv[8 * kk + e];
                z0 = fmaxf(z0, SLOPE * z0);
                z1 = fmaxf(z1, SLOPE * z1);
                a0[e] = f2bf(z0); a1[e] = f2bf(z1);
            }
        } else {
#pragma unroll
            for (int e = 0; e < 8; ++e) {
                a0[e] = f2bf(xv0[8 * (kk - 2) + e]);
                a1[e] = f2bf(xv1[8 * (kk - 2) + e]);
            }
        }
        const short8* wf = (const short8*)Wcs + kk * 4 * 64;
#pragma unroll
        for (int nf = 0; nf < 4; ++nf) {
            short8 bfv = wf[nf * 64 + l];
            acc[0][nf] = __builtin_amdgcn_mfma_f32_16x16x32_bf16(a0, bfv, acc[0][nf], 0, 0, 0);
            acc[1][nf] = __builtin_amdgcn_mfma_f32_16x16x32_bf16(a1, bfv, acc[1][nf], 0, 0, 0);
        }
    }

    float* ob = out + (size_t)b * COUT * NSV;
#pragma unroll
    for (int mf = 0; mf < 2; ++mf)
#pragma unroll
        for (int nf = 0; nf < 4; ++nf) {
            const int o  = 16 * nf + r;
            const int sr = s0 + 16 * mf + 4 * g;
            f32x4 d = acc[mf][nf];
            const float bb = bcs[o];
            float* p = ob + (size_t)o * NSV + sr;
            if (sr + 3 < NSV) {
                // rows only 8B-aligned (NSV*4 % 16 == 8) -> two float2 stores
                *(float2*)(p)     = make_float2(d[0] + bb, d[1] + bb);
                *(float2*)(p + 2) = make_float2(d[2] + bb, d[3] + bb);
            } else {
#pragma unroll
                for (int rr = 0; rr < 4; ++rr)
                    if (sr + rr < NSV) p[rr] = d[rr] + bb;
            }
        }
}

extern "C" void kernel_launch(void* const* d_in, const int* in_sizes, int n_in,
                              void* d_out, int out_size, void* d_ws, size_t ws_size,
                              hipStream_t stream) {
    const float* x          = (const float*)d_in[0];
    const float* x1         = (const float*)d_in[1];
    const int*   pool_neigh = (const int*)d_in[2];
    const int*   neigh      = (const int*)d_in[3];
    const float* W1         = (const float*)d_in[4];
    // d_in[5] = b1: cancels exactly through BatchNorm
    const float* gamma      = (const float*)d_in[6];
    const float* beta       = (const float*)d_in[7];
    const float* Wc         = (const float*)d_in[8];
    const float* bc         = (const float*)d_in[9];

    char* wsb = (char*)d_ws;
    short* xt     = (short*)(wsb + O_XT);
    short* hbf    = (short*)(wsb + O_H);
    short* pooled = (short*)(wsb + O_POOL);
    short* W1f    = (short*)(wsb + O_W1F);
    short* Wcf    = (short*)(wsb + O_WCF);
    float* stats  = (float*)(wsb + O_ST);
    float* out    = (float*)d_out;

    k_prep<<<1, 256, 0, stream>>>(W1, Wc, W1f, Wcf, stats);
    k_transpose<<<dim3((NFINE + 127) / 128, NB), 256, 0, stream>>>(x, xt);
    k_pool<<<dim3((NSV + 255) / 256, NB), 256, 0, stream>>>(xt, pool_neigh, pooled);
    k_conv<<<dim3((NSV + 127) / 128, NB), 256, 0, stream>>>(neigh, W1f, pooled, hbf, stats);
    k_stats<<<1, 64, 0, stream>>>(gamma, beta, stats);
    k_out<<<dim3((NSV + 127) / 128, NB), 256, 0, stream>>>(hbf, x1, Wcf, stats, bc, out);
}

// Round 5
// 276.628 us; speedup vs baseline: 1.2396x; 1.2396x over previous
//
#include <hip/hip_runtime.h>
#include <cstddef>

#define NB    4
#define CIN   32
#define COUT  64
#define NFINE 163842
#define NSV   40962
#define EPSB  1e-5f
#define SLOPE 0.2f

typedef __attribute__((ext_vector_type(8))) short short8;
typedef __attribute__((ext_vector_type(4))) float f32x4;

// ws layout (bytes):
//   O_XT  : xt bf16 [B][NFINE][32] (41.9 MB) -- dead after k_pool
//   O_H   : h  bf16 [B][NSV][64]   (21 MB)   -- aliases xt (written after k_pool)
//   O_POOL: pooled bf16 [B][NSV][32] (10.5 MB)
//   O_W1F : W1 frag-major bf16 (28 KB)
//   O_WCF : Wc frag-major bf16 (16 KB)
//   O_ST  : f32 sum[64] sq[64]
#define O_XT   ((size_t)0)
#define O_H    ((size_t)0)
#define O_POOL ((size_t)48 << 20)
#define O_W1F  ((size_t)60 << 20)
#define O_WCF  ((size_t)60 << 20 | 0x8000)
#define O_ST   ((size_t)61 << 20)

static __device__ __forceinline__ short f2bf(float f) {
    union { float f; unsigned u; } v; v.f = f;
    unsigned r = v.u + 0x7fffu + ((v.u >> 16) & 1u);   // RNE
    return (short)(r >> 16);
}
static __device__ __forceinline__ float bf2f(short h) {
    union { unsigned u; float f; } v;
    v.u = ((unsigned)(unsigned short)h) << 16;
    return v.f;
}

// x [B][CIN][NFINE] f32 -> xt [B][NFINE][CIN] bf16
// Block (0,0) additionally: zero stats + build frag-major W1f/Wcf.
//   W1f: [kk<7][nf<4][l<64][e<8], o=16nf+(l&15), k=32kk+8(l>>4)+e
//   Wcf: [kk<4][nf<4][l<64][e<8], o=16nf+(l&15), c=32kk+8(l>>4)+e
__global__ __launch_bounds__(256) void k_transpose(
        const float* __restrict__ x, short* __restrict__ xt,
        const float* __restrict__ W1, const float* __restrict__ Wc,
        short* __restrict__ W1f, short* __restrict__ Wcf,
        float* __restrict__ stats) {
    __shared__ float tile[128][33];
    const int n0 = blockIdx.x * 128;
    const int b  = blockIdx.y;
    const float* xb = x + (size_t)b * CIN * NFINE;
#pragma unroll
    for (int q = 0; q < 16; ++q) {
        int i = threadIdx.x + 256 * q;
        int c = i >> 7, nl = i & 127;
        int n = n0 + nl;
        tile[nl][c] = (n < NFINE) ? xb[(size_t)c * NFINE + n] : 0.f;
    }
    __syncthreads();
#pragma unroll
    for (int q = 0; q < 2; ++q) {
        int i = threadIdx.x + 256 * q;
        int nl = i >> 2, cg = i & 3;
        int n = n0 + nl;
        if (n >= NFINE) continue;
        short8 o;
#pragma unroll
        for (int e = 0; e < 8; ++e) o[e] = f2bf(tile[nl][8 * cg + e]);
        *(short8*)(xt + ((size_t)b * NFINE + n) * CIN + 8 * cg) = o;
    }
    if (blockIdx.x == 0 && blockIdx.y == 0) {
        if (threadIdx.x < 128) stats[threadIdx.x] = 0.f;
        for (int i = threadIdx.x; i < 7 * 4 * 64 * 8; i += 256) {
            int e = i & 7, l = (i >> 3) & 63, nf = (i >> 9) & 3, kk = i >> 11;
            int o = 16 * nf + (l & 15);
            int k = 32 * kk + 8 * (l >> 4) + e;
            W1f[i] = f2bf(W1[o * (7 * CIN) + k]);
        }
        for (int i = threadIdx.x; i < 4 * 4 * 64 * 8; i += 256) {
            int e = i & 7, l = (i >> 3) & 63, nf = (i >> 9) & 3, kk = i >> 11;
            int o = 16 * nf + (l & 15);
            int c = 32 * kk + 8 * (l >> 4) + e;
            Wcf[i] = f2bf(Wc[o * (2 * COUT) + c]);
        }
    }
}

// pooled[b][s][c] = mean_j xt[b][pool_neigh[7s+j]][c]
// 4 threads per vertex: thread = (s, 16B quarter-row). All 7 gathers in flight.
__global__ __launch_bounds__(256) void k_pool(
        const short* __restrict__ xt, const int* __restrict__ pn,
        short* __restrict__ pooled) {
    const int gid = blockIdx.x * 256 + threadIdx.x;
    const int s = gid >> 2, gq = gid & 3;
    const int b = blockIdx.y;
    if (s >= NSV) return;
    int t[7];
#pragma unroll
    for (int j = 0; j < 7; ++j) t[j] = pn[7 * s + j];
    const short* xb = xt + (size_t)b * NFINE * CIN + 8 * gq;
    short8 v[7];
#pragma unroll
    for (int j = 0; j < 7; ++j)
        v[j] = *(const short8*)(xb + (size_t)t[j] * CIN);
    float a8[8];
#pragma unroll
    for (int e = 0; e < 8; ++e) a8[e] = 0.f;
#pragma unroll
    for (int j = 0; j < 7; ++j)
#pragma unroll
        for (int e = 0; e < 8; ++e) a8[e] += bf2f(v[j][e]);
    short8 o;
#pragma unroll
    for (int e = 0; e < 8; ++e) o[e] = f2bf(a8[e] * (1.f / 7.f));
    *(short8*)(pooled + ((size_t)b * NSV + s) * CIN + 8 * gq) = o;
}

// MFMA conv: h[b][s][o] = sum_k A[s][k] * W1T[k][o]  (K=224, b1 cancels in BN)
__global__ __launch_bounds__(256) void k_conv(
        const int* __restrict__ neigh, const short* __restrict__ W1f,
        const short* __restrict__ pooled, short* __restrict__ hbf,
        float* __restrict__ stats) {
    __shared__ float red[2][4][COUT];
    const int l = threadIdx.x & 63, w = threadIdx.x >> 6;
    const int b = blockIdx.y;
    const int s0 = blockIdx.x * 128 + w * 32;
    const int r = l & 15, g = l >> 4;

    const short* pb = pooled + (size_t)b * NSV * CIN;
    const int sA0 = s0 + r, sA1 = s0 + 16 + r;
    const bool v0 = sA0 < NSV, v1 = sA1 < NSV;
    const int c0 = v0 ? sA0 : NSV - 1, c1 = v1 ? sA1 : NSV - 1;

    int t0[7], t1[7];
#pragma unroll
    for (int kk = 0; kk < 7; ++kk) { t0[kk] = neigh[7 * c0 + kk]; t1[kk] = neigh[7 * c1 + kk]; }

    short8 a0[7], a1[7];
#pragma unroll
    for (int kk = 0; kk < 7; ++kk) {
        a0[kk] = *(const short8*)(pb + (size_t)t0[kk] * CIN + 8 * g);
        a1[kk] = *(const short8*)(pb + (size_t)t1[kk] * CIN + 8 * g);
    }

    f32x4 acc[2][4];
#pragma unroll
    for (int mf = 0; mf < 2; ++mf)
#pragma unroll
        for (int nf = 0; nf < 4; ++nf) acc[mf][nf] = (f32x4){0.f, 0.f, 0.f, 0.f};

#pragma unroll
    for (int kk = 0; kk < 7; ++kk) {
        const short8* wf = (const short8*)(W1f) + (size_t)kk * 256;
#pragma unroll
        for (int nf = 0; nf < 4; ++nf) {
            short8 bfv = wf[nf * 64 + l];
            acc[0][nf] = __builtin_amdgcn_mfma_f32_16x16x32_bf16(a0[kk], bfv, acc[0][nf], 0, 0, 0);
            acc[1][nf] = __builtin_amdgcn_mfma_f32_16x16x32_bf16(a1[kk], bfv, acc[1][nf], 0, 0, 0);
        }
    }

    float sum[4], sq[4];
#pragma unroll
    for (int nf = 0; nf < 4; ++nf) { sum[nf] = 0.f; sq[nf] = 0.f; }
#pragma unroll
    for (int mf = 0; mf < 2; ++mf)
#pragma unroll
        for (int nf = 0; nf < 4; ++nf) {
            f32x4 d = acc[mf][nf];
#pragma unroll
            for (int rr = 0; rr < 4; ++rr) {
                const int srow = s0 + 16 * mf + 4 * g + rr;
                const float v = d[rr];
                const bool ok = srow < NSV;
                if (ok) hbf[((size_t)b * NSV + srow) * COUT + 16 * nf + r] = f2bf(v);
                const float vm = ok ? v : 0.f;
                sum[nf] += vm; sq[nf] += vm * vm;
            }
        }
#pragma unroll
    for (int nf = 0; nf < 4; ++nf) {
        float a = sum[nf], c = sq[nf];
        a += __shfl_xor(a, 16); a += __shfl_xor(a, 32);
        c += __shfl_xor(c, 16); c += __shfl_xor(c, 32);
        if (g == 0) { red[0][w][16 * nf + r] = a; red[1][w][16 * nf + r] = c; }
    }
    __syncthreads();
    if (threadIdx.x < COUT) {
        const int o = threadIdx.x;
        atomicAdd(&stats[o],        red[0][0][o] + red[0][1][o] + red[0][2][o] + red[0][3][o]);
        atomicAdd(&stats[COUT + o], red[1][0][o] + red[1][1][o] + red[1][2][o] + red[1][3][o]);
    }
}

// MFMA out: out[b][o][s] = sum_c A[s][c] * WcT[c][o] + bc[o]
//   A[s][0:64]   = leaky(sc*h[b][s][:]+sh)  (from hbf, bf16)
//   A[s][64:128] = x1[b][:][s]              (read directly, f32)
// BN finalize (mu/var -> scale/shift) recomputed per block from stats sums.
__global__ __launch_bounds__(256) void k_out(
        const short* __restrict__ hbf, const float* __restrict__ x1,
        const short* __restrict__ Wcf, const float* __restrict__ st,
        const float* __restrict__ gamma, const float* __restrict__ beta,
        const float* __restrict__ bc, float* __restrict__ out) {
    __shared__ __attribute__((aligned(16))) short Wcs[4 * 4 * 64 * 8]; // 16KB
    __shared__ float scs[COUT], shs[COUT], bcs[COUT];
    {
        const short8* src = (const short8*)Wcf;
        short8* dst = (short8*)Wcs;
        for (int i = threadIdx.x; i < 1024; i += 256) dst[i] = src[i];
        if (threadIdx.x < COUT) {
            const int o = threadIdx.x;
            const float cnt = (float)((size_t)NB * NSV);
            float mu  = st[o] / cnt;
            float var = st[COUT + o] / cnt - mu * mu;
            float sc  = gamma[o] * rsqrtf(var + EPSB);
            scs[o] = sc;
            shs[o] = beta[o] - mu * sc;
            bcs[o] = bc[o];
        }
    }
    __syncthreads();

    const int l = threadIdx.x & 63, w = threadIdx.x >> 6;
    const int b = blockIdx.y;
    const int s0 = blockIdx.x * 128 + w * 32;
    const int r = l & 15, g = l >> 4;

    int sa0 = s0 + r;       if (sa0 > NSV - 1) sa0 = NSV - 1;
    int sa1 = s0 + 16 + r;  if (sa1 > NSV - 1) sa1 = NSV - 1;
    const size_t rowA0 = ((size_t)b * NSV + sa0) * COUT;
    const size_t rowA1 = ((size_t)b * NSV + sa1) * COUT;

    short8 h00 = *(const short8*)(hbf + rowA0 + 8 * g);
    short8 h01 = *(const short8*)(hbf + rowA0 + 32 + 8 * g);
    short8 h10 = *(const short8*)(hbf + rowA1 + 8 * g);
    short8 h11 = *(const short8*)(hbf + rowA1 + 32 + 8 * g);
    const float* x1b = x1 + (size_t)b * COUT * NSV;
    float xv0[16], xv1[16];
#pragma unroll
    for (int i = 0; i < 16; ++i) {
        const int c2 = 32 * (i >> 3) + 8 * g + (i & 7);
        xv0[i] = x1b[(size_t)c2 * NSV + sa0];
        xv1[i] = x1b[(size_t)c2 * NSV + sa1];
    }

    float scv[16], shv[16];
#pragma unroll
    for (int kk = 0; kk < 2; ++kk)
#pragma unroll
        for (int e = 0; e < 8; ++e) {
            scv[8 * kk + e] = scs[32 * kk + 8 * g + e];
            shv[8 * kk + e] = shs[32 * kk + 8 * g + e];
        }

    f32x4 acc[2][4];
#pragma unroll
    for (int mf = 0; mf < 2; ++mf)
#pragma unroll
        for (int nf = 0; nf < 4; ++nf) acc[mf][nf] = (f32x4){0.f, 0.f, 0.f, 0.f};

#pragma unroll
    for (int kk = 0; kk < 4; ++kk) {
        short8 a0, a1;
        if (kk < 2) {
            short8 hh0 = kk ? h01 : h00;
            short8 hh1 = kk ? h11 : h10;
#pragma unroll
            for (int e = 0; e < 8; ++e) {
                float z0 = scv[8 * kk + e] * bf2f(hh0[e]) + shv[8 * kk + e];
                float z1 = scv[8 * kk + e] * bf2f(hh1[e]) + shv[8 * kk + e];
                z0 = fmaxf(z0, SLOPE * z0);
                z1 = fmaxf(z1, SLOPE * z1);
                a0[e] = f2bf(z0); a1[e] = f2bf(z1);
            }
        } else {
#pragma unroll
            for (int e = 0; e < 8; ++e) {
                a0[e] = f2bf(xv0[8 * (kk - 2) + e]);
                a1[e] = f2bf(xv1[8 * (kk - 2) + e]);
            }
        }
        const short8* wf = (const short8*)Wcs + kk * 4 * 64;
#pragma unroll
        for (int nf = 0; nf < 4; ++nf) {
            short8 bfv = wf[nf * 64 + l];
            acc[0][nf] = __builtin_amdgcn_mfma_f32_16x16x32_bf16(a0, bfv, acc[0][nf], 0, 0, 0);
            acc[1][nf] = __builtin_amdgcn_mfma_f32_16x16x32_bf16(a1, bfv, acc[1][nf], 0, 0, 0);
        }
    }

    float* ob = out + (size_t)b * COUT * NSV;
#pragma unroll
    for (int mf = 0; mf < 2; ++mf)
#pragma unroll
        for (int nf = 0; nf < 4; ++nf) {
            const int o  = 16 * nf + r;
            const int sr = s0 + 16 * mf + 4 * g;
            f32x4 d = acc[mf][nf];
            const float bb = bcs[o];
            float* p = ob + (size_t)o * NSV + sr;
            if (sr + 3 < NSV) {
                // rows only 8B-aligned (NSV*4 % 16 == 8) -> two float2 stores
                *(float2*)(p)     = make_float2(d[0] + bb, d[1] + bb);
                *(float2*)(p + 2) = make_float2(d[2] + bb, d[3] + bb);
            } else {
#pragma unroll
                for (int rr = 0; rr < 4; ++rr)
                    if (sr + rr < NSV) p[rr] = d[rr] + bb;
            }
        }
}

extern "C" void kernel_launch(void* const* d_in, const int* in_sizes, int n_in,
                              void* d_out, int out_size, void* d_ws, size_t ws_size,
                              hipStream_t stream) {
    const float* x          = (const float*)d_in[0];
    const float* x1         = (const float*)d_in[1];
    const int*   pool_neigh = (const int*)d_in[2];
    const int*   neigh      = (const int*)d_in[3];
    const float* W1         = (const float*)d_in[4];
    // d_in[5] = b1: cancels exactly through BatchNorm
    const float* gamma      = (const float*)d_in[6];
    const float* beta       = (const float*)d_in[7];
    const float* Wc         = (const float*)d_in[8];
    const float* bc         = (const float*)d_in[9];

    char* wsb = (char*)d_ws;
    short* xt     = (short*)(wsb + O_XT);
    short* hbf    = (short*)(wsb + O_H);
    short* pooled = (short*)(wsb + O_POOL);
    short* W1f    = (short*)(wsb + O_W1F);
    short* Wcf    = (short*)(wsb + O_WCF);
    float* stats  = (float*)(wsb + O_ST);
    float* out    = (float*)d_out;

    k_transpose<<<dim3((NFINE + 127) / 128, NB), 256, 0, stream>>>(
        x, xt, W1, Wc, W1f, Wcf, stats);
    k_pool<<<dim3((NSV * 4 + 255) / 256, NB), 256, 0, stream>>>(xt, pool_neigh, pooled);
    k_conv<<<dim3((NSV + 127) / 128, NB), 256, 0, stream>>>(neigh, W1f, pooled, hbf, stats);
    k_out<<<dim3((NSV + 127) / 128, NB), 256, 0, stream>>>(
        hbf, x1, Wcf, stats, gamma, beta, bc, out);
}